// Round 20
// baseline (736.471 us; speedup 1.0000x reference)
//
#include <hip/hip_runtime.h>
#include <hip/hip_bf16.h>

// GAT attention aggregator, fused. B=20000, N=32, D=128, H=256, O=128.
// R20 = R13 structure at MB=2: LDS 19.8 KB -> 8 blocks/CU (32 waves = full
// occupancy, was 16). 10000 blocks x 256 thr. Same swapped-operand score,
// 4 barriers, VGPR target 64 (R13 compiled to 64 naturally). Per-CU memory
// traffic unchanged; bet is doubled latency-hiding depth.

#define BB 20000
#define NN 32
#define DD 128
#define HH 256
#define OO 128
#define MB 2
#define GRID (BB / MB)   // 10000
#define XR 64            // x rows 64..65, agg rows 66..67, junk 68..71

typedef __bf16 bf16x8 __attribute__((ext_vector_type(8)));
typedef __bf16 bf16x4 __attribute__((ext_vector_type(4)));
typedef float f32x4 __attribute__((ext_vector_type(4)));

__device__ __forceinline__ float bf2f(unsigned short s) {
    return __builtin_bit_cast(float, ((unsigned)s) << 16);
}

__global__ void prep_weights(const float* __restrict__ Watt,
                             const float* __restrict__ Wfcx,
                             const float* __restrict__ Wfcn,
                             __bf16* __restrict__ WaT,
                             __bf16* __restrict__ WcT) {
    int idx = blockIdx.x * 256 + threadIdx.x;   // 0..65535
    int half = idx >> 15;
    int j = idx & 32767;
    int c = j >> 7, k = j & 127;
    if (half == 0) {
        WaT[j] = (__bf16)Watt[k * HH + c];       // WaT[h][k] = W_att[k][h]
    } else {
        float wv = (c < OO) ? Wfcx[k * OO + c] : Wfcn[k * OO + (c - OO)];
        WcT[j] = (__bf16)wv;                     // WcT[c][k]
    }
}

__launch_bounds__(256, 8)
__global__ void gat_fused(const float* __restrict__ x,
                          const float* __restrict__ neibs,
                          const float* __restrict__ a,
                          const __bf16* __restrict__ WaT,
                          const __bf16* __restrict__ WcT,
                          float* __restrict__ out) {
    __shared__ __bf16 rowsS[72 * 128];           // 18,432 B: 64 neib + x/agg/junk
    __shared__ float e_part[4][72];              //  1,152 B
    __shared__ float att_s[2][32];               //    256 B  -> 19,840 B total

    // ---- round-1 desync ----
    {
        const unsigned bid = blockIdx.x;
        if (bid < 2048) {
            const unsigned k = (bid * 2654435761u) >> 30;
            for (unsigned i = 0; i < k; ++i)
                __builtin_amdgcn_s_sleep(40);
        }
    }

    const int tid = threadIdx.x;
    const int w   = tid >> 6;      // wave 0..3
    const int l   = tid & 63;
    const int lr  = l & 15;
    const int lg  = l >> 4;
    const int b0  = blockIdx.x * MB;
    char* rbase = (char*)rowsS;

    // staging: row = it*8 + (tid>>5); byte (row*256 + 2k) ^ ((row&7)<<4)
    const int stbase = (tid >> 5) * 256 + ((8 * (tid & 31)) ^ ((tid >> 5) << 4));
    int abase[4], fbase[4];
    const int lc = lr & 7;                        // clamped row for x/final tile
#pragma unroll
    for (int ks = 0; ks < 4; ++ks) {
        abase[ks] = lr * 256 + ((ks * 64 + lg * 16) ^ ((lr & 7) << 4));
        fbase[ks] = lc * 256 + ((ks * 64 + lg * 16) ^ (lc << 4));
    }

    // ---- stage 64 neib rows (8 float4/thread) + 2 x rows ----
    {
        const float4* np4 = (const float4*)(neibs + (size_t)b0 * NN * DD);
#pragma unroll
        for (int it = 0; it < 8; ++it) {
            float4 v = np4[it * 256 + tid];
            bf16x4 s = { (__bf16)v.x, (__bf16)v.y, (__bf16)v.z, (__bf16)v.w };
            *(bf16x4*)(rbase + stbase + it * 2048) = s;
        }
        if (tid < 64) {                           // x rows 64..65
            float4 v = ((const float4*)(x + (size_t)b0 * DD))[tid];
            bf16x4 s = { (__bf16)v.x, (__bf16)v.y, (__bf16)v.z, (__bf16)v.w };
            *(bf16x4*)(rbase + stbase + XR * 256) = s;
        }
    }

    // ---- W_att panel (A-operand) + neighbor a-coefs ----
    bf16x8 bw[4][4];
    float cN[4][4];
#pragma unroll
    for (int c4 = 0; c4 < 4; ++c4) {
        int col = (w * 4 + c4) * 16 + lr;
#pragma unroll
        for (int ks = 0; ks < 4; ++ks)
            bw[c4][ks] = *(const bf16x8*)(WaT + col * 128 + ks * 32 + lg * 8);
#pragma unroll
        for (int i = 0; i < 4; ++i)
            cN[c4][i] = a[HH + (w * 4 + c4) * 16 + 4 * lg + i];
    }

    __syncthreads();                              // B1: staged rows visible

    // ---- score (swapped): 4 neib row-tiles ----
#pragma unroll
    for (int rt = 0; rt < 4; ++rt) {
        bf16x8 af[4];
#pragma unroll
        for (int ks = 0; ks < 4; ++ks)
            af[ks] = *(const bf16x8*)(rbase + abase[ks] + rt * 4096);
        f32x4 acc[4];
#pragma unroll
        for (int c4 = 0; c4 < 4; ++c4) acc[c4] = (f32x4){0.f, 0.f, 0.f, 0.f};
#pragma unroll
        for (int ks = 0; ks < 4; ++ks)
#pragma unroll
            for (int c4 = 0; c4 < 4; ++c4)
                acc[c4] = __builtin_amdgcn_mfma_f32_16x16x32_bf16(bw[c4][ks], af[ks], acc[c4], 0, 0, 0);
        float ep = 0.f;
#pragma unroll
        for (int c4 = 0; c4 < 4; ++c4)
#pragma unroll
            for (int i = 0; i < 4; ++i) {
                float v = acc[c4][i];
                ep = fmaf(cN[c4][i], fmaxf(v, 0.01f * v), ep);
            }
        ep += __shfl_xor(ep, 16);
        ep += __shfl_xor(ep, 32);
        if (l < 16) e_part[w][rt * 16 + l] = ep;
    }
    // peeled x-tile: clamped rows 64+(lr&7); only rows 64..65 meaningful
    {
        float cX[4][4];
#pragma unroll
        for (int c4 = 0; c4 < 4; ++c4)
#pragma unroll
            for (int i = 0; i < 4; ++i)
                cX[c4][i] = a[(w * 4 + c4) * 16 + 4 * lg + i];
        bf16x8 af[4];
#pragma unroll
        for (int ks = 0; ks < 4; ++ks)
            af[ks] = *(const bf16x8*)(rbase + fbase[ks] + XR * 256);
        f32x4 acc[4];
#pragma unroll
        for (int c4 = 0; c4 < 4; ++c4) acc[c4] = (f32x4){0.f, 0.f, 0.f, 0.f};
#pragma unroll
        for (int ks = 0; ks < 4; ++ks)
#pragma unroll
            for (int c4 = 0; c4 < 4; ++c4)
                acc[c4] = __builtin_amdgcn_mfma_f32_16x16x32_bf16(bw[c4][ks], af[ks], acc[c4], 0, 0, 0);
        float ep = 0.f;
#pragma unroll
        for (int c4 = 0; c4 < 4; ++c4)
#pragma unroll
            for (int i = 0; i < 4; ++i) {
                float v = acc[c4][i];
                ep = fmaf(cX[c4][i], fmaxf(v, 0.01f * v), ep);
            }
        ep += __shfl_xor(ep, 16);
        ep += __shfl_xor(ep, 32);
        if (l < 8) e_part[w][XR + l] = ep;        // rows 64..71; 64..65 read
    }
    __syncthreads();                              // B2: e_part complete

    // ---- softmax over 32 neighbors (threads 0..63; node = tid>>5) ----
    if (tid < 64) {
        const int bloc = tid >> 5;
        const int nloc = tid & 31;
        float sn = e_part[0][tid] + e_part[1][tid] + e_part[2][tid] + e_part[3][tid];
        const int xr = XR + bloc;
        float sx = e_part[0][xr] + e_part[1][xr] + e_part[2][xr] + e_part[3][xr];
        float e = sx + sn;
        e = (e > 0.f) ? e : 0.2f * e;
        float mx = e;
#pragma unroll
        for (int m = 16; m >= 1; m >>= 1) mx = fmaxf(mx, __shfl_xor(mx, m, 32));
        float ex = __expf(e - mx);
        float sum = ex;
#pragma unroll
        for (int m = 16; m >= 1; m >>= 1) sum += __shfl_xor(sum, m, 32);
        att_s[bloc][nloc] = ex / sum;
    }
    __syncthreads();                              // B3: att_s ready

    // ---- WcT panel loads issue here; latency hides under aggregation ----
    bf16x8 bff[4][4];
#pragma unroll
    for (int c4 = 0; c4 < 4; ++c4)
#pragma unroll
        for (int ks = 0; ks < 4; ++ks)
            bff[c4][ks] = *(const bf16x8*)(WcT + ((w * 4 + c4) * 16 + lr) * 128 + ks * 32 + lg * 8);

    // ---- aggregation: wave (node=w>>1, dh=w&1); lane owns d = dh*64+l ----
    {
        const int node = w >> 1, dh = w & 1;
        const int d = dh * 64 + l;
        float ag = 0.f;
#pragma unroll 8
        for (int n = 0; n < 32; ++n) {
            int row = node * 32 + n;
            unsigned off = (unsigned)(row * 256) + ((2 * d) ^ ((row & 7) << 4));
            ag = fmaf(att_s[node][n], bf2f(*(const unsigned short*)(rbase + off)), ag);
        }
        int row = 66 + node;                      // agg rows 66..67 (row&7 = 2,3)
        unsigned off = (unsigned)(row * 256) + ((2 * d) ^ ((row & 7) << 4));
        *(__bf16*)(rbase + off) = (__bf16)ag;
    }
    __syncthreads();                              // B4: agg rows visible

    // ---- final: [x0,x1,agg0,agg1,junk](rows 64..71) @ WcT^T, masked ----
    {
        bf16x8 af[4];
#pragma unroll
        for (int ks = 0; ks < 4; ++ks)
            af[ks] = *(const bf16x8*)(rbase + fbase[ks] + XR * 256);
        f32x4 acc[4];
#pragma unroll
        for (int c4 = 0; c4 < 4; ++c4) acc[c4] = (f32x4){0.f, 0.f, 0.f, 0.f};
#pragma unroll
        for (int ks = 0; ks < 4; ++ks)
#pragma unroll
            for (int c4 = 0; c4 < 4; ++c4)
                acc[c4] = __builtin_amdgcn_mfma_f32_16x16x32_bf16(af[ks], bff[c4][ks], acc[c4], 0, 0, 0);
#pragma unroll
        for (int c4 = 0; c4 < 4; ++c4) {
            int col = (w * 4 + c4) * 16 + lr;
#pragma unroll
            for (int reg = 0; reg < 4; ++reg) {
                int i = lg * 4 + reg;             // 0=x0 1=x1 2=agg0 3=agg1, 4+ junk
                bool doit = (i < 2) ? (col < 128) : (i < 4 && col >= 128);
                if (doit) {
                    float v = fmaxf(acc[c4][reg], 0.f);
                    out[(size_t)(b0 + (i & 1)) * 256 + col] = v;
                }
            }
        }
    }
}

extern "C" void kernel_launch(void* const* d_in, const int* in_sizes, int n_in,
                              void* d_out, int out_size, void* d_ws, size_t ws_size,
                              hipStream_t stream) {
    const float* x    = (const float*)d_in[0];
    const float* nb   = (const float*)d_in[1];
    const float* Watt = (const float*)d_in[2];
    const float* Wfcx = (const float*)d_in[3];
    const float* Wfcn = (const float*)d_in[4];
    const float* a    = (const float*)d_in[5];
    __bf16* WaT = (__bf16*)d_ws;
    __bf16* WcT = WaT + 32768;
    float* o = (float*)d_out;

    prep_weights<<<256, 256, 0, stream>>>(Watt, Wfcx, Wfcn, WaT, WcT);
    gat_fused<<<GRID, 256, 0, stream>>>(x, nb, a, WaT, WcT, o);
}

// Round 21
// 186.855 us; speedup vs baseline: 3.9414x; 3.9414x over previous
//
#include <hip/hip_runtime.h>
#include <hip/hip_bf16.h>

// GAT attention aggregator, fused. B=20000, N=32, D=128, H=256, O=128.
// R21 = R20 with launch_bounds(256,4): R20's (256,8) forced a 32-VGPR
// allocation -> total spill (WRITE_SIZE 1.13GB, 736us). The 2nd launch_bounds
// arg only constrains the COMPILER; HW occupancy comes from actual VGPR/LDS.
// With cap 128 the working set compiles to ~64 VGPR (R13 proof), and LDS
// 19.9KB lets HW run 8 blocks/CU = 32 waves (R20 measured 89.5% occupancy).

#define BB 20000
#define NN 32
#define DD 128
#define HH 256
#define OO 128
#define MB 2
#define GRID (BB / MB)   // 10000
#define XR 64            // x rows 64..65, agg rows 66..67, junk 68..71

typedef __bf16 bf16x8 __attribute__((ext_vector_type(8)));
typedef __bf16 bf16x4 __attribute__((ext_vector_type(4)));
typedef float f32x4 __attribute__((ext_vector_type(4)));

__device__ __forceinline__ float bf2f(unsigned short s) {
    return __builtin_bit_cast(float, ((unsigned)s) << 16);
}

__global__ void prep_weights(const float* __restrict__ Watt,
                             const float* __restrict__ Wfcx,
                             const float* __restrict__ Wfcn,
                             __bf16* __restrict__ WaT,
                             __bf16* __restrict__ WcT) {
    int idx = blockIdx.x * 256 + threadIdx.x;   // 0..65535
    int half = idx >> 15;
    int j = idx & 32767;
    int c = j >> 7, k = j & 127;
    if (half == 0) {
        WaT[j] = (__bf16)Watt[k * HH + c];       // WaT[h][k] = W_att[k][h]
    } else {
        float wv = (c < OO) ? Wfcx[k * OO + c] : Wfcn[k * OO + (c - OO)];
        WcT[j] = (__bf16)wv;                     // WcT[c][k]
    }
}

__launch_bounds__(256, 4)
__global__ void gat_fused(const float* __restrict__ x,
                          const float* __restrict__ neibs,
                          const float* __restrict__ a,
                          const __bf16* __restrict__ WaT,
                          const __bf16* __restrict__ WcT,
                          float* __restrict__ out) {
    __shared__ __bf16 rowsS[72 * 128];           // 18,432 B: 64 neib + x/agg/junk
    __shared__ float e_part[4][72];              //  1,152 B
    __shared__ float att_s[2][32];               //    256 B  -> 19,840 B total

    // ---- round-1 desync ----
    {
        const unsigned bid = blockIdx.x;
        if (bid < 2048) {
            const unsigned k = (bid * 2654435761u) >> 30;
            for (unsigned i = 0; i < k; ++i)
                __builtin_amdgcn_s_sleep(40);
        }
    }

    const int tid = threadIdx.x;
    const int w   = tid >> 6;      // wave 0..3
    const int l   = tid & 63;
    const int lr  = l & 15;
    const int lg  = l >> 4;
    const int b0  = blockIdx.x * MB;
    char* rbase = (char*)rowsS;

    // staging: row = it*8 + (tid>>5); byte (row*256 + 2k) ^ ((row&7)<<4)
    const int stbase = (tid >> 5) * 256 + ((8 * (tid & 31)) ^ ((tid >> 5) << 4));
    int abase[4], fbase[4];
    const int lc = lr & 7;                        // clamped row for x/final tile
#pragma unroll
    for (int ks = 0; ks < 4; ++ks) {
        abase[ks] = lr * 256 + ((ks * 64 + lg * 16) ^ ((lr & 7) << 4));
        fbase[ks] = lc * 256 + ((ks * 64 + lg * 16) ^ (lc << 4));
    }

    // ---- stage 64 neib rows (8 float4/thread) + 2 x rows ----
    {
        const float4* np4 = (const float4*)(neibs + (size_t)b0 * NN * DD);
#pragma unroll
        for (int it = 0; it < 8; ++it) {
            float4 v = np4[it * 256 + tid];
            bf16x4 s = { (__bf16)v.x, (__bf16)v.y, (__bf16)v.z, (__bf16)v.w };
            *(bf16x4*)(rbase + stbase + it * 2048) = s;
        }
        if (tid < 64) {                           // x rows 64..65
            float4 v = ((const float4*)(x + (size_t)b0 * DD))[tid];
            bf16x4 s = { (__bf16)v.x, (__bf16)v.y, (__bf16)v.z, (__bf16)v.w };
            *(bf16x4*)(rbase + stbase + XR * 256) = s;
        }
    }

    // ---- W_att panel (A-operand) + neighbor a-coefs ----
    bf16x8 bw[4][4];
    float cN[4][4];
#pragma unroll
    for (int c4 = 0; c4 < 4; ++c4) {
        int col = (w * 4 + c4) * 16 + lr;
#pragma unroll
        for (int ks = 0; ks < 4; ++ks)
            bw[c4][ks] = *(const bf16x8*)(WaT + col * 128 + ks * 32 + lg * 8);
#pragma unroll
        for (int i = 0; i < 4; ++i)
            cN[c4][i] = a[HH + (w * 4 + c4) * 16 + 4 * lg + i];
    }

    __syncthreads();                              // B1: staged rows visible

    // ---- score (swapped): 4 neib row-tiles ----
#pragma unroll
    for (int rt = 0; rt < 4; ++rt) {
        bf16x8 af[4];
#pragma unroll
        for (int ks = 0; ks < 4; ++ks)
            af[ks] = *(const bf16x8*)(rbase + abase[ks] + rt * 4096);
        f32x4 acc[4];
#pragma unroll
        for (int c4 = 0; c4 < 4; ++c4) acc[c4] = (f32x4){0.f, 0.f, 0.f, 0.f};
#pragma unroll
        for (int ks = 0; ks < 4; ++ks)
#pragma unroll
            for (int c4 = 0; c4 < 4; ++c4)
                acc[c4] = __builtin_amdgcn_mfma_f32_16x16x32_bf16(bw[c4][ks], af[ks], acc[c4], 0, 0, 0);
        float ep = 0.f;
#pragma unroll
        for (int c4 = 0; c4 < 4; ++c4)
#pragma unroll
            for (int i = 0; i < 4; ++i) {
                float v = acc[c4][i];
                ep = fmaf(cN[c4][i], fmaxf(v, 0.01f * v), ep);
            }
        ep += __shfl_xor(ep, 16);
        ep += __shfl_xor(ep, 32);
        if (l < 16) e_part[w][rt * 16 + l] = ep;
    }
    // peeled x-tile: clamped rows 64+(lr&7); only rows 64..65 meaningful
    {
        float cX[4][4];
#pragma unroll
        for (int c4 = 0; c4 < 4; ++c4)
#pragma unroll
            for (int i = 0; i < 4; ++i)
                cX[c4][i] = a[(w * 4 + c4) * 16 + 4 * lg + i];
        bf16x8 af[4];
#pragma unroll
        for (int ks = 0; ks < 4; ++ks)
            af[ks] = *(const bf16x8*)(rbase + fbase[ks] + XR * 256);
        f32x4 acc[4];
#pragma unroll
        for (int c4 = 0; c4 < 4; ++c4) acc[c4] = (f32x4){0.f, 0.f, 0.f, 0.f};
#pragma unroll
        for (int ks = 0; ks < 4; ++ks)
#pragma unroll
            for (int c4 = 0; c4 < 4; ++c4)
                acc[c4] = __builtin_amdgcn_mfma_f32_16x16x32_bf16(bw[c4][ks], af[ks], acc[c4], 0, 0, 0);
        float ep = 0.f;
#pragma unroll
        for (int c4 = 0; c4 < 4; ++c4)
#pragma unroll
            for (int i = 0; i < 4; ++i) {
                float v = acc[c4][i];
                ep = fmaf(cX[c4][i], fmaxf(v, 0.01f * v), ep);
            }
        ep += __shfl_xor(ep, 16);
        ep += __shfl_xor(ep, 32);
        if (l < 8) e_part[w][XR + l] = ep;        // rows 64..71; 64..65 read
    }
    __syncthreads();                              // B2: e_part complete

    // ---- softmax over 32 neighbors (threads 0..63; node = tid>>5) ----
    if (tid < 64) {
        const int bloc = tid >> 5;
        const int nloc = tid & 31;
        float sn = e_part[0][tid] + e_part[1][tid] + e_part[2][tid] + e_part[3][tid];
        const int xr = XR + bloc;
        float sx = e_part[0][xr] + e_part[1][xr] + e_part[2][xr] + e_part[3][xr];
        float e = sx + sn;
        e = (e > 0.f) ? e : 0.2f * e;
        float mx = e;
#pragma unroll
        for (int m = 16; m >= 1; m >>= 1) mx = fmaxf(mx, __shfl_xor(mx, m, 32));
        float ex = __expf(e - mx);
        float sum = ex;
#pragma unroll
        for (int m = 16; m >= 1; m >>= 1) sum += __shfl_xor(sum, m, 32);
        att_s[bloc][nloc] = ex / sum;
    }
    __syncthreads();                              // B3: att_s ready

    // ---- WcT panel loads issue here; latency hides under aggregation ----
    bf16x8 bff[4][4];
#pragma unroll
    for (int c4 = 0; c4 < 4; ++c4)
#pragma unroll
        for (int ks = 0; ks < 4; ++ks)
            bff[c4][ks] = *(const bf16x8*)(WcT + ((w * 4 + c4) * 16 + lr) * 128 + ks * 32 + lg * 8);

    // ---- aggregation: wave (node=w>>1, dh=w&1); lane owns d = dh*64+l ----
    {
        const int node = w >> 1, dh = w & 1;
        const int d = dh * 64 + l;
        float ag = 0.f;
#pragma unroll 8
        for (int n = 0; n < 32; ++n) {
            int row = node * 32 + n;
            unsigned off = (unsigned)(row * 256) + ((2 * d) ^ ((row & 7) << 4));
            ag = fmaf(att_s[node][n], bf2f(*(const unsigned short*)(rbase + off)), ag);
        }
        int row = 66 + node;                      // agg rows 66..67 (row&7 = 2,3)
        unsigned off = (unsigned)(row * 256) + ((2 * d) ^ ((row & 7) << 4));
        *(__bf16*)(rbase + off) = (__bf16)ag;
    }
    __syncthreads();                              // B4: agg rows visible

    // ---- final: [x0,x1,agg0,agg1,junk](rows 64..71) @ WcT^T, masked ----
    {
        bf16x8 af[4];
#pragma unroll
        for (int ks = 0; ks < 4; ++ks)
            af[ks] = *(const bf16x8*)(rbase + fbase[ks] + XR * 256);
        f32x4 acc[4];
#pragma unroll
        for (int c4 = 0; c4 < 4; ++c4) acc[c4] = (f32x4){0.f, 0.f, 0.f, 0.f};
#pragma unroll
        for (int ks = 0; ks < 4; ++ks)
#pragma unroll
            for (int c4 = 0; c4 < 4; ++c4)
                acc[c4] = __builtin_amdgcn_mfma_f32_16x16x32_bf16(af[ks], bff[c4][ks], acc[c4], 0, 0, 0);
#pragma unroll
        for (int c4 = 0; c4 < 4; ++c4) {
            int col = (w * 4 + c4) * 16 + lr;
#pragma unroll
            for (int reg = 0; reg < 4; ++reg) {
                int i = lg * 4 + reg;             // 0=x0 1=x1 2=agg0 3=agg1, 4+ junk
                bool doit = (i < 2) ? (col < 128) : (i < 4 && col >= 128);
                if (doit) {
                    float v = fmaxf(acc[c4][reg], 0.f);
                    out[(size_t)(b0 + (i & 1)) * 256 + col] = v;
                }
            }
        }
    }
}

extern "C" void kernel_launch(void* const* d_in, const int* in_sizes, int n_in,
                              void* d_out, int out_size, void* d_ws, size_t ws_size,
                              hipStream_t stream) {
    const float* x    = (const float*)d_in[0];
    const float* nb   = (const float*)d_in[1];
    const float* Watt = (const float*)d_in[2];
    const float* Wfcx = (const float*)d_in[3];
    const float* Wfcn = (const float*)d_in[4];
    const float* a    = (const float*)d_in[5];
    __bf16* WaT = (__bf16*)d_ws;
    __bf16* WcT = WaT + 32768;
    float* o = (float*)d_out;

    prep_weights<<<256, 256, 0, stream>>>(Watt, Wfcx, Wfcn, WaT, WcT);
    gat_fused<<<GRID, 256, 0, stream>>>(x, nb, a, WaT, WcT, o);
}